// Round 1
// baseline (2490.040 us; speedup 1.0000x reference)
//
#include <hip/hip_runtime.h>
#include <hip/hip_bf16.h>
#include <math.h>

#define D_MODEL 1024
#define NH 16
#define DK 64
#define BB 8
#define SS 1024
#define MTOT (BB * SS) /* 8192 */

typedef float f4v __attribute__((ext_vector_type(4)));

// ---------------------------------------------------------------------------
// GEMM: C[M,N] = X[M,K] @ W[N,K]^T + bias[N]   (K = D_MODEL = 1024)
// BM = BN = 128, BK = 32, 256 threads, per-thread 2x2 groups of 4x4.
// HEADED=1: write Y in [B, H, S, DK] layout (for Q/K/V). HEADED=0: [M, N].
// ---------------------------------------------------------------------------
template <int HEADED>
__global__ __launch_bounds__(256) void gemm_xwt(const float* __restrict__ X,
                                                const float* __restrict__ W,
                                                const float* __restrict__ bias,
                                                float* __restrict__ Y) {
    __shared__ float Xs[32][132];  // transposed: Xs[k][m]
    __shared__ float Ws[32][132];  // transposed: Ws[k][n]

    const int tid = threadIdx.x;
    const int tx = tid & 15;   // 0..15 -> col groups
    const int ty = tid >> 4;   // 0..15 -> row groups
    const int m0 = blockIdx.y * 128;
    const int n0 = blockIdx.x * 128;

    float acc[2][2][4][4];
#pragma unroll
    for (int ri = 0; ri < 2; ++ri)
#pragma unroll
        for (int ci = 0; ci < 2; ++ci)
#pragma unroll
            for (int i = 0; i < 4; ++i)
#pragma unroll
                for (int j = 0; j < 4; ++j) acc[ri][ci][i][j] = 0.0f;

    for (int kt = 0; kt < D_MODEL / 32; ++kt) {
        const int k0 = kt * 32;
        // stage tiles (transposed into LDS)
#pragma unroll
        for (int p = 0; p < 4; ++p) {
            const int r = (tid >> 3) + p * 32;  // 0..127
            const int c4 = tid & 7;             // k quad
            f4v xv = *(const f4v*)&X[(size_t)(m0 + r) * D_MODEL + k0 + 4 * c4];
            Xs[4 * c4 + 0][r] = xv[0];
            Xs[4 * c4 + 1][r] = xv[1];
            Xs[4 * c4 + 2][r] = xv[2];
            Xs[4 * c4 + 3][r] = xv[3];
            f4v wv = *(const f4v*)&W[(size_t)(n0 + r) * D_MODEL + k0 + 4 * c4];
            Ws[4 * c4 + 0][r] = wv[0];
            Ws[4 * c4 + 1][r] = wv[1];
            Ws[4 * c4 + 2][r] = wv[2];
            Ws[4 * c4 + 3][r] = wv[3];
        }
        __syncthreads();
#pragma unroll
        for (int kk = 0; kk < 32; ++kk) {
            f4v a[2], b[2];
            a[0] = *(const f4v*)&Xs[kk][4 * ty];
            a[1] = *(const f4v*)&Xs[kk][4 * ty + 64];
            b[0] = *(const f4v*)&Ws[kk][4 * tx];
            b[1] = *(const f4v*)&Ws[kk][4 * tx + 64];
#pragma unroll
            for (int ri = 0; ri < 2; ++ri)
#pragma unroll
                for (int ci = 0; ci < 2; ++ci)
#pragma unroll
                    for (int i = 0; i < 4; ++i)
#pragma unroll
                        for (int j = 0; j < 4; ++j)
                            acc[ri][ci][i][j] += a[ri][i] * b[ci][j];
        }
        __syncthreads();
    }

    // epilogue: add bias, store
#pragma unroll
    for (int ri = 0; ri < 2; ++ri) {
#pragma unroll
        for (int ci = 0; ci < 2; ++ci) {
            const int colbase = n0 + 64 * ci + 4 * tx;
            f4v bv = *(const f4v*)&bias[colbase];
#pragma unroll
            for (int i = 0; i < 4; ++i) {
                const int row = m0 + 64 * ri + 4 * ty + i;
                f4v o;
#pragma unroll
                for (int j = 0; j < 4; ++j) o[j] = acc[ri][ci][i][j] + bv[j];
                if (HEADED) {
                    const int bb = row >> 10;          // / SS
                    const int sr = row & (SS - 1);
                    const int h = colbase >> 6;        // / DK
                    const int d = colbase & (DK - 1);
                    *(f4v*)&Y[(((size_t)bb * NH + h) * SS + sr) * DK + d] = o;
                } else {
                    *(f4v*)&Y[(size_t)row * D_MODEL + colbase] = o;
                }
            }
        }
    }
}

// ---------------------------------------------------------------------------
// Flash attention (fp32): Q,K,V in [B,H,S,DK]; ctx out in [B,S,D_MODEL].
// Block: 128 threads; Q tile 64 rows; KV tiles of 64; online softmax.
// Thread (tx,ty): rows r = ty + 8*i (i<8), cols c = 4*tx + j (j<4).
// ---------------------------------------------------------------------------
__global__ __launch_bounds__(128) void attn_kernel(const float* __restrict__ Q,
                                                   const float* __restrict__ K,
                                                   const float* __restrict__ V,
                                                   float* __restrict__ ctx) {
    __shared__ float Qs[64][68];  // [qrow][d]
    __shared__ float Kt[64][68];  // [d][key]  (transposed)
    __shared__ float Vs[64][68];  // [key][d]
    __shared__ float Ps[64][68];  // [qrow][key]

    const int tid = threadIdx.x;
    const int tx = tid & 15;
    const int ty = tid >> 4;  // 0..7
    const int bh = blockIdx.x;
    const int q0 = blockIdx.y * 64;

    const float* Qb = Q + ((size_t)bh * SS + q0) * DK;
    const float* Kb = K + (size_t)bh * SS * DK;
    const float* Vb = V + (size_t)bh * SS * DK;

    // stage Q tile once
#pragma unroll
    for (int p = 0; p < 8; ++p) {
        const int idx = p * 128 + tid;  // float4 index 0..1023
        const int r = idx >> 4, c4 = idx & 15;
        *(f4v*)&Qs[r][4 * c4] = *(const f4v*)&Qb[(size_t)r * DK + 4 * c4];
    }

    float m_i[8], l_i[8], O[8][4];
#pragma unroll
    for (int i = 0; i < 8; ++i) {
        m_i[i] = -1e30f;
        l_i[i] = 0.0f;
#pragma unroll
        for (int j = 0; j < 4; ++j) O[i][j] = 0.0f;
    }

    for (int t = 0; t < SS / 64; ++t) {
        const float* Kt0 = Kb + (size_t)t * 64 * DK;
        const float* Vt0 = Vb + (size_t)t * 64 * DK;
        __syncthreads();  // previous iteration done with Kt/Vs/Ps (also orders Qs stage)
#pragma unroll
        for (int p = 0; p < 8; ++p) {
            const int idx = p * 128 + tid;
            const int r = idx >> 4, c4 = idx & 15;
            f4v kv = *(const f4v*)&Kt0[(size_t)r * DK + 4 * c4];
            Kt[4 * c4 + 0][r] = kv[0];
            Kt[4 * c4 + 1][r] = kv[1];
            Kt[4 * c4 + 2][r] = kv[2];
            Kt[4 * c4 + 3][r] = kv[3];
            *(f4v*)&Vs[r][4 * c4] = *(const f4v*)&Vt0[(size_t)r * DK + 4 * c4];
        }
        __syncthreads();

        // scores: s[i][j] = Q[row]·K[col]
        float s[8][4];
#pragma unroll
        for (int i = 0; i < 8; ++i)
#pragma unroll
            for (int j = 0; j < 4; ++j) s[i][j] = 0.0f;
#pragma unroll
        for (int d4 = 0; d4 < 16; ++d4) {
            f4v qv[8], kv[4];
#pragma unroll
            for (int i = 0; i < 8; ++i) qv[i] = *(const f4v*)&Qs[ty + 8 * i][4 * d4];
#pragma unroll
            for (int u = 0; u < 4; ++u) kv[u] = *(const f4v*)&Kt[4 * d4 + u][4 * tx];
#pragma unroll
            for (int i = 0; i < 8; ++i)
#pragma unroll
                for (int j = 0; j < 4; ++j)
                    s[i][j] += qv[i][0] * kv[0][j] + qv[i][1] * kv[1][j] +
                               qv[i][2] * kv[2][j] + qv[i][3] * kv[3][j];
        }

        // online softmax update
#pragma unroll
        for (int i = 0; i < 8; ++i) {
#pragma unroll
            for (int j = 0; j < 4; ++j) s[i][j] *= 0.125f;  // 1/sqrt(DK)
            float mx = fmaxf(fmaxf(s[i][0], s[i][1]), fmaxf(s[i][2], s[i][3]));
            mx = fmaxf(mx, __shfl_xor(mx, 1));
            mx = fmaxf(mx, __shfl_xor(mx, 2));
            mx = fmaxf(mx, __shfl_xor(mx, 4));
            mx = fmaxf(mx, __shfl_xor(mx, 8));
            const float mnew = fmaxf(m_i[i], mx);
            const float corr = __expf(m_i[i] - mnew);
            f4v p;
            float rs = 0.0f;
#pragma unroll
            for (int j = 0; j < 4; ++j) {
                p[j] = __expf(s[i][j] - mnew);
                rs += p[j];
            }
            rs += __shfl_xor(rs, 1);
            rs += __shfl_xor(rs, 2);
            rs += __shfl_xor(rs, 4);
            rs += __shfl_xor(rs, 8);
            l_i[i] = l_i[i] * corr + rs;
            m_i[i] = mnew;
#pragma unroll
            for (int j = 0; j < 4; ++j) O[i][j] *= corr;
            *(f4v*)&Ps[ty + 8 * i][4 * tx] = p;
        }
        __syncthreads();

        // O += P @ V
#pragma unroll
        for (int k4 = 0; k4 < 16; ++k4) {
            f4v pv[8], vv[4];
#pragma unroll
            for (int i = 0; i < 8; ++i) pv[i] = *(const f4v*)&Ps[ty + 8 * i][4 * k4];
#pragma unroll
            for (int u = 0; u < 4; ++u) vv[u] = *(const f4v*)&Vs[4 * k4 + u][4 * tx];
#pragma unroll
            for (int i = 0; i < 8; ++i)
#pragma unroll
                for (int j = 0; j < 4; ++j)
                    O[i][j] += pv[i][0] * vv[0][j] + pv[i][1] * vv[1][j] +
                               pv[i][2] * vv[2][j] + pv[i][3] * vv[3][j];
        }
    }

    // normalize + store ctx in [B, S, D_MODEL] with col = h*DK + c
    const int b = bh >> 4;   // / NH
    const int h = bh & 15;
#pragma unroll
    for (int i = 0; i < 8; ++i) {
        const int r = ty + 8 * i;
        const float inv = 1.0f / l_i[i];
        f4v o;
#pragma unroll
        for (int j = 0; j < 4; ++j) o[j] = O[i][j] * inv;
        *(f4v*)&ctx[((size_t)b * SS + (q0 + r)) * D_MODEL + h * DK + 4 * tx] = o;
    }
}

// ---------------------------------------------------------------------------
extern "C" void kernel_launch(void* const* d_in, const int* in_sizes, int n_in,
                              void* d_out, int out_size, void* d_ws, size_t ws_size,
                              hipStream_t stream) {
    const float* query = (const float*)d_in[0];
    const float* key_  = (const float*)d_in[1];
    const float* value = (const float*)d_in[2];
    const float* w_q = (const float*)d_in[3];
    const float* b_q = (const float*)d_in[4];
    const float* w_k = (const float*)d_in[5];
    const float* b_k = (const float*)d_in[6];
    const float* w_v = (const float*)d_in[7];
    const float* b_v = (const float*)d_in[8];
    const float* w_o = (const float*)d_in[9];
    const float* b_o = (const float*)d_in[10];

    float* ws = (float*)d_ws;
    const size_t SZ = (size_t)MTOT * D_MODEL;  // 8,388,608 floats
    float* qb = ws;
    float* kb = ws + SZ;
    float* vb = ws + 2 * SZ;
    float* cb = ws + 3 * SZ;

    const dim3 gg(D_MODEL / 128, MTOT / 128);  // (8, 64)
    gemm_xwt<1><<<gg, 256, 0, stream>>>(query, w_q, b_q, qb);
    gemm_xwt<1><<<gg, 256, 0, stream>>>(key_, w_k, b_k, kb);
    gemm_xwt<1><<<gg, 256, 0, stream>>>(value, w_v, b_v, vb);

    attn_kernel<<<dim3(BB * NH, SS / 64), 128, 0, stream>>>(qb, kb, vb, cb);

    gemm_xwt<0><<<gg, 256, 0, stream>>>(cb, w_o, b_o, (float*)d_out);
}

// Round 2
// 388.000 us; speedup vs baseline: 6.4176x; 6.4176x over previous
//
#include <hip/hip_runtime.h>
#include <hip/hip_bf16.h>

#define NH 16
#define DK 64
#define BB 8
#define SS 1024
#define DM 1024
#define MTOT (BB * SS) /* 8192 */

typedef float f4v __attribute__((ext_vector_type(4)));
typedef short s16v8 __attribute__((ext_vector_type(8)));
typedef unsigned short u16v4 __attribute__((ext_vector_type(4)));
typedef unsigned short u16v8 __attribute__((ext_vector_type(8)));

// round-to-nearest-even f32 -> bf16 bits
__device__ __forceinline__ unsigned short f2bf(float x) {
    unsigned int u = __float_as_uint(x);
    u += 0x7FFFu + ((u >> 16) & 1u);
    return (unsigned short)(u >> 16);
}

// async global->LDS, 16B per lane (dest must be linear in lane order)
__device__ __forceinline__ void gload16(const void* g, void* l) {
    __builtin_amdgcn_global_load_lds(
        (const __attribute__((address_space(1))) void*)g,
        (__attribute__((address_space(3))) void*)l, 16, 0, 0);
}

// ---------------------------------------------------------------------------
// Convert all fp32 inputs to bf16, concatenated in ws:
// [query(8M) key(8M) value(8M) wq(1M) wk(1M) wv(1M) wo(1M)] elements.
// ---------------------------------------------------------------------------
struct Src7 { const float* p[7]; };

__global__ __launch_bounds__(256) void cvt_all(Src7 sp, unsigned short* __restrict__ dst) {
    const size_t e = ((size_t)blockIdx.x * 256 + threadIdx.x) * 8;
    const int unit = (int)(e >> 20);
    int t; size_t base;
    if (unit < 8)       { t = 0; base = 0; }
    else if (unit < 16) { t = 1; base = (size_t)8 << 20; }
    else if (unit < 24) { t = 2; base = (size_t)16 << 20; }
    else                { t = 3 + (unit - 24); base = (size_t)unit << 20; }
    const float* s = sp.p[t] + (e - base);
    f4v a = *(const f4v*)s;
    f4v b = *(const f4v*)(s + 4);
    u16v8 o;
    o[0] = f2bf(a[0]); o[1] = f2bf(a[1]); o[2] = f2bf(a[2]); o[3] = f2bf(a[3]);
    o[4] = f2bf(b[0]); o[5] = f2bf(b[1]); o[6] = f2bf(b[2]); o[7] = f2bf(b[3]);
    *(u16v8*)(dst + e) = o;
}

// ---------------------------------------------------------------------------
// bf16 MFMA GEMM: C[M,N] = X[M,K] @ W[N,K]^T + bias, K = 1024.
// m97 structure: 128x128 tile, BK=32, 256 threads (4 waves, 2x2), 4x4 MFMA
// tiles per wave, global_load_lds width-16 staging, LDS [128][32] row-major.
// MODE 0: fp32 out [M][DM].  MODE 1: bf16 headed out [b,h,s,d].
// ---------------------------------------------------------------------------
template <int MODE>
__global__ __launch_bounds__(256) void gemm_bf16(const unsigned short* __restrict__ X,
                                                 const unsigned short* __restrict__ W,
                                                 const float* __restrict__ bias,
                                                 void* __restrict__ Yv) {
    __shared__ unsigned short As[128 * 32];
    __shared__ unsigned short Bs[128 * 32];
    const int tid = threadIdx.x;
    const int wv = tid >> 6, l = tid & 63;
    const int lq = l & 15, g = l >> 4;
    const int wr = wv >> 1, wc = wv & 1;
    const int m0 = blockIdx.y * 128, n0 = blockIdx.x * 128;

    f4v acc[4][4];
#pragma unroll
    for (int i = 0; i < 4; ++i)
#pragma unroll
        for (int j = 0; j < 4; ++j) acc[i][j] = (f4v){0.f, 0.f, 0.f, 0.f};

    for (int kt = 0; kt < DM / 32; ++kt) {
        const int k0 = kt * 32;
        __syncthreads();  // all waves done reading previous tile
#pragma unroll
        for (int p = 0; p < 2; ++p) {
            const int u = p * 256 + tid;        // 16B unit: row=u>>2, kchunk=u&3
            const int row = u >> 2, kc = u & 3;
            gload16(X + (size_t)(m0 + row) * DM + k0 + kc * 8, As + (size_t)u * 8);
            gload16(W + (size_t)(n0 + row) * DM + k0 + kc * 8, Bs + (size_t)u * 8);
        }
        __syncthreads();  // drains vmcnt -> LDS ready

        s16v8 a[4], b[4];
#pragma unroll
        for (int i = 0; i < 4; ++i)
            a[i] = *(const s16v8*)(As + (wr * 64 + i * 16 + lq) * 32 + g * 8);
#pragma unroll
        for (int j = 0; j < 4; ++j)
            b[j] = *(const s16v8*)(Bs + (wc * 64 + j * 16 + lq) * 32 + g * 8);
#pragma unroll
        for (int i = 0; i < 4; ++i)
#pragma unroll
            for (int j = 0; j < 4; ++j)
                acc[i][j] = __builtin_amdgcn_mfma_f32_16x16x32_bf16(a[i], b[j], acc[i][j], 0, 0, 0);
    }

    // epilogue: D layout col = lane&15, row = (lane>>4)*4 + reg
#pragma unroll
    for (int j = 0; j < 4; ++j) {
        const int col = n0 + wc * 64 + j * 16 + lq;
        const float bv = bias[col];
#pragma unroll
        for (int i = 0; i < 4; ++i) {
#pragma unroll
            for (int r = 0; r < 4; ++r) {
                const int row = m0 + wr * 64 + i * 16 + g * 4 + r;
                const float val = acc[i][j][r] + bv;
                if (MODE == 0) {
                    ((float*)Yv)[(size_t)row * DM + col] = val;
                } else {
                    const int b_ = row >> 10, s_ = row & (SS - 1);
                    const int h_ = col >> 6, d_ = col & (DK - 1);
                    ((unsigned short*)Yv)[((size_t)(b_ * NH + h_) * SS + s_) * DK + d_] = f2bf(val);
                }
            }
        }
    }
}

// ---------------------------------------------------------------------------
// Transpose V: [b,h,key,d] -> [b,h,d,key] (bf16), 64x64 tiles.
// ---------------------------------------------------------------------------
__global__ __launch_bounds__(256) void transpose_v(const unsigned short* __restrict__ Vp,
                                                   unsigned short* __restrict__ VpT) {
    __shared__ unsigned short Ts[64][68];
    const int bx = blockIdx.x;
    const int bh = bx >> 4, kt = bx & 15;
    const unsigned short* src = Vp + (size_t)bh * (SS * DK) + (size_t)kt * 64 * DK;
    unsigned short* dst = VpT + (size_t)bh * (SS * DK) + kt * 64;
    const int t = threadIdx.x;
#pragma unroll
    for (int p = 0; p < 4; ++p) {
        const int idx = p * 1024 + t * 4;
        const int key = idx >> 6, d = idx & 63;
        *(u16v4*)&Ts[key][d] = *(const u16v4*)(src + (size_t)key * DK + d);
    }
    __syncthreads();
#pragma unroll
    for (int p = 0; p < 4; ++p) {
        const int idx = p * 1024 + t * 4;
        const int d = idx >> 6, k4 = idx & 63;
        u16v4 o;
        o[0] = Ts[k4 + 0][d]; o[1] = Ts[k4 + 1][d];
        o[2] = Ts[k4 + 2][d]; o[3] = Ts[k4 + 3][d];
        *(u16v4*)(dst + (size_t)d * SS + k4) = o;
    }
}

// ---------------------------------------------------------------------------
// Flash attention, bf16 MFMA. Qp,Kp [b,h,s,64]; Vt [b,h,64,s] (pre-transposed).
// Block = 256 thr (4 waves), 64 q-rows/block (16/wave), KV tiles of 64.
// LDS k-blocked layouts so all fragment ds_read_b128 are conflict-light:
//   Ks[kb][key][8]  (kb = d/8), Vs[kbt][d][8] (kbt = key/8), staged linearly
//   via global_load_lds with permuted 16B-granular global sources.
// Softmax rows live in the MFMA D layout (lane holds 4 q-rows, 16 lanes = key).
// ---------------------------------------------------------------------------
__global__ __launch_bounds__(256) void attn_mfma(const unsigned short* __restrict__ Qp,
                                                 const unsigned short* __restrict__ Kp,
                                                 const unsigned short* __restrict__ Vt,
                                                 unsigned short* __restrict__ ctx) {
    __shared__ unsigned short Ks[4096];
    __shared__ unsigned short Vs[4096];
    __shared__ unsigned short Ps[4][16 * 72];  // per-wave P, stride 72 (16B-aligned, low-conflict)
    const int tid = threadIdx.x;
    const int wv = tid >> 6, l = tid & 63;
    const int lq = l & 15, g = l >> 4;
    const int bh = blockIdx.x, q0 = blockIdx.y * 64;

    const unsigned short* Qb = Qp + ((size_t)bh * SS + q0 + wv * 16) * DK;
    const unsigned short* Kb = Kp + (size_t)bh * SS * DK;
    const unsigned short* Vb = Vt + (size_t)bh * DK * SS;  // rows = d, len SS

    // Q fragments straight from global: lane holds row lq, d = kk*32 + g*8 + e
    s16v8 qf[2];
    qf[0] = *(const s16v8*)(Qb + lq * DK + g * 8);
    qf[1] = *(const s16v8*)(Qb + lq * DK + 32 + g * 8);

    f4v O[4];
#pragma unroll
    for (int od = 0; od < 4; ++od) O[od] = (f4v){0.f, 0.f, 0.f, 0.f};
    float m_r[4] = {-1e30f, -1e30f, -1e30f, -1e30f};
    float l_r[4] = {0.f, 0.f, 0.f, 0.f};

    for (int t = 0; t < SS / 64; ++t) {
        __syncthreads();  // all waves done with previous K/V tile
#pragma unroll
        for (int p = 0; p < 2; ++p) {
            const int u = p * 256 + tid;
            // K tile: layout [kb=u>>6][key=u&63][8], src = K[t*64+key][kb*8..]
            gload16(Kb + (size_t)(t * 64 + (u & 63)) * DK + (u >> 6) * 8, Ks + (size_t)u * 8);
            // V tile: layout [kbt=u>>6][d=u&63][8], src = Vt[d][t*64 + kbt*8..]
            gload16(Vb + (size_t)(u & 63) * SS + t * 64 + (u >> 6) * 8, Vs + (size_t)u * 8);
        }
        __syncthreads();  // vmcnt drained -> tiles ready

        // S = Q K^T : s[ct] covers keys ct*16+lq, rows g*4+r
        f4v s[4];
#pragma unroll
        for (int ct = 0; ct < 4; ++ct) s[ct] = (f4v){0.f, 0.f, 0.f, 0.f};
#pragma unroll
        for (int kk = 0; kk < 2; ++kk) {
#pragma unroll
            for (int ct = 0; ct < 4; ++ct) {
                s16v8 kf = *(const s16v8*)(Ks + ((kk * 4 + g) * 64 + ct * 16 + lq) * 8);
                s[ct] = __builtin_amdgcn_mfma_f32_16x16x32_bf16(qf[kk], kf, s[ct], 0, 0, 0);
            }
        }

        // online softmax (scale 1/8); reductions across lq via shfl_xor 1,2,4,8
        float rs[4], corr[4];
#pragma unroll
        for (int r = 0; r < 4; ++r) {
            float v = fmaxf(fmaxf(s[0][r], s[1][r]), fmaxf(s[2][r], s[3][r])) * 0.125f;
            v = fmaxf(v, __shfl_xor(v, 1));
            v = fmaxf(v, __shfl_xor(v, 2));
            v = fmaxf(v, __shfl_xor(v, 4));
            v = fmaxf(v, __shfl_xor(v, 8));
            const float mn = fmaxf(m_r[r], v);
            corr[r] = __expf(m_r[r] - mn);
            m_r[r] = mn;
            rs[r] = 0.f;
        }
#pragma unroll
        for (int ct = 0; ct < 4; ++ct) {
#pragma unroll
            for (int r = 0; r < 4; ++r) {
                const float p = __expf(s[ct][r] * 0.125f - m_r[r]);
                rs[r] += p;
                Ps[wv][(g * 4 + r) * 72 + ct * 16 + lq] = f2bf(p);
            }
        }
#pragma unroll
        for (int r = 0; r < 4; ++r) {
            float x = rs[r];
            x += __shfl_xor(x, 1);
            x += __shfl_xor(x, 2);
            x += __shfl_xor(x, 4);
            x += __shfl_xor(x, 8);
            l_r[r] = l_r[r] * corr[r] + x;
        }
#pragma unroll
        for (int od = 0; od < 4; ++od) {
            f4v o = O[od];
            o[0] *= corr[0]; o[1] *= corr[1]; o[2] *= corr[2]; o[3] *= corr[3];
            O[od] = o;
        }

        __builtin_amdgcn_s_waitcnt(0);  // P writes (incl. other lanes) visible within wave

        // O += P V : A-frag = P row lq, keys kk2*32+g*8+e ; B-frag = V col d
#pragma unroll
        for (int kk2 = 0; kk2 < 2; ++kk2) {
            s16v8 pf = *(const s16v8*)(Ps[wv] + lq * 72 + kk2 * 32 + g * 8);
#pragma unroll
            for (int od = 0; od < 4; ++od) {
                s16v8 vf = *(const s16v8*)(Vs + ((kk2 * 4 + g) * 64 + od * 16 + lq) * 8);
                O[od] = __builtin_amdgcn_mfma_f32_16x16x32_bf16(pf, vf, O[od], 0, 0, 0);
            }
        }
    }

    // normalize + store ctx[b][s][h*64+d] as bf16
    const int b_ = bh >> 4, h_ = bh & 15;
#pragma unroll
    for (int r = 0; r < 4; ++r) {
        const float inv = 1.0f / l_r[r];
        const int sq = q0 + wv * 16 + g * 4 + r;
#pragma unroll
        for (int od = 0; od < 4; ++od) {
            const int d_ = od * 16 + lq;
            ctx[((size_t)b_ * SS + sq) * DM + h_ * DK + d_] = f2bf(O[od][r] * inv);
        }
    }
}

// ---------------------------------------------------------------------------
extern "C" void kernel_launch(void* const* d_in, const int* in_sizes, int n_in,
                              void* d_out, int out_size, void* d_ws, size_t ws_size,
                              hipStream_t stream) {
    const float* query = (const float*)d_in[0];
    const float* key_  = (const float*)d_in[1];
    const float* value = (const float*)d_in[2];
    const float* w_q = (const float*)d_in[3];
    const float* b_q = (const float*)d_in[4];
    const float* w_k = (const float*)d_in[5];
    const float* b_k = (const float*)d_in[6];
    const float* w_v = (const float*)d_in[7];
    const float* b_v = (const float*)d_in[8];
    const float* w_o = (const float*)d_in[9];
    const float* b_o = (const float*)d_in[10];

    unsigned short* ws = (unsigned short*)d_ws;
    const size_t NX = (size_t)MTOT * DM;  // 8,388,608
    const size_t NW = (size_t)DM * DM;    // 1,048,576
    unsigned short* xq  = ws;
    unsigned short* xk  = xq + NX;
    unsigned short* xv  = xk + NX;
    unsigned short* wqb = xv + NX;
    unsigned short* wkb = wqb + NW;
    unsigned short* wvb = wkb + NW;
    unsigned short* wob = wvb + NW;
    unsigned short* Qp  = wob + NW;
    unsigned short* Kp  = Qp + NX;
    unsigned short* Vp  = Kp + NX;
    unsigned short* VpT = Vp + NX;
    unsigned short* ctx = Vp;  // alias: Vp dead after transpose
    // high-water: 3*NX + 4*NW + 4*NX = 125,829,120 bytes < 128 MB

    Src7 sp;
    sp.p[0] = query; sp.p[1] = key_; sp.p[2] = value;
    sp.p[3] = w_q; sp.p[4] = w_k; sp.p[5] = w_v; sp.p[6] = w_o;
    cvt_all<<<14336, 256, 0, stream>>>(sp, ws);

    const dim3 gg(DM / 128, MTOT / 128);  // (8, 64)
    gemm_bf16<1><<<gg, 256, 0, stream>>>(xq, wqb, b_q, Qp);
    gemm_bf16<1><<<gg, 256, 0, stream>>>(xk, wkb, b_k, Kp);
    gemm_bf16<1><<<gg, 256, 0, stream>>>(xv, wvb, b_v, Vp);

    transpose_v<<<2048, 256, 0, stream>>>(Vp, VpT);

    attn_mfma<<<dim3(BB * NH, SS / 64), 256, 0, stream>>>(Qp, Kp, VpT, ctx);

    gemm_bf16<0><<<gg, 256, 0, stream>>>(ctx, wob, b_o, (float*)d_out);
}